// Round 11
// baseline (228.981 us; speedup 1.0000x reference)
//
#include <hip/hip_runtime.h>
#include <hip/hip_bf16.h>

#define N_NODES 50000
#define N_EDGES 800000
#define F_IN    256
#define C_DIM   64
#define HC      128   // H*C
#define NPG     6250  // nodes per XCD group (N/8)

typedef __attribute__((ext_vector_type(8))) short bf16x8;
typedef __attribute__((ext_vector_type(4))) float f32x4;

// ---------------- workspace layout (bytes) ----------------
static constexpr size_t OFF_HBF   = 0;           // u32  h packed  [N][64] = 12.8 MB
static constexpr size_t OFF_H2    = 12800000;    // u32  h2 packed [N][64] = 12.8 MB
static constexpr size_t OFF_AB    = 25600000;    // u32  ab packed [N][64] = 12.8 MB
static constexpr size_t OFF_AS    = 38400000;    // f32 [N][2]
static constexpr size_t OFF_AD    = 38800000;
static constexpr size_t OFF_OFFS  = 39200000;    // i32 N+1
static constexpr size_t OFF_DEG   = 39400064;
static constexpr size_t OFF_CUR   = 39600064;
static constexpr size_t OFF_PART  = 39800064;
static constexpr size_t OFF_CSR2  = 39801088;    // int2 [E] (src,eid) = 6.4 MB
static constexpr size_t OFF_WTAB  = 46201088;    // float2 [E] edge-order weights = 6.4 MB
static constexpr size_t OFF_WT    = 52601088;    // bf16 Wt   [128][256] = 64 KB
static constexpr size_t OFF_FC1T  = 52666624;    // bf16 fc1t [128][128] = 32 KB
static constexpr size_t OFF_SCALE = 52699392;    // f32 [128]
static constexpr size_t OFF_CC    = 52699904;    // f32 [128]
static constexpr size_t OFF_FC2M  = 52700416;    // bf16 fc2m [2][64][8] = 2 KB

__device__ __forceinline__ float2 bf2(unsigned u) {
    float2 r;
    r.x = __uint_as_float(u << 16);
    r.y = __uint_as_float(u & 0xffff0000u);
    return r;
}
__device__ __forceinline__ unsigned short f2bf(float f) {
    unsigned u = __float_as_uint(f);
    return (unsigned short)((u + 0x7fffu + ((u >> 16) & 1u)) >> 16);  // RNE
}
__device__ __forceinline__ short f2bf_s(float f) {
    __hip_bfloat16 h = __float2bfloat16(f);        // compiler pairs into v_cvt_pk_bf16_f32
    return *reinterpret_cast<short*>(&h);
}
// packed-channel mapping: word q (0..63) of a row holds channels (c0(q), c0(q)+16),
// c0(q) = 32*(q>>4) + (q&15)

// ---------------- prep: Wt, fc1t, fc2m, BN scale/cc, deg zero ----------------
__global__ __launch_bounds__(256) void k_prep(const float* __restrict__ W,
                                              const float* __restrict__ fc1,
                                              const float* __restrict__ fc1_b,
                                              const float* __restrict__ gamma,
                                              const float* __restrict__ beta,
                                              const float* __restrict__ mean,
                                              const float* __restrict__ var,
                                              const float* __restrict__ fc2_w,
                                              unsigned short* __restrict__ Wt,
                                              unsigned short* __restrict__ fc1t,
                                              float* __restrict__ scale,
                                              float* __restrict__ cc,
                                              unsigned short* __restrict__ fc2m,
                                              int* __restrict__ deg) {
    int id = blockIdx.x * 256 + threadIdx.x;
    if (id < N_NODES) deg[id] = 0;
    if (id < 32768) {                       // Wt[n][k] = bf16(W[k][n])
        int n = id >> 8, k = id & 255;
        Wt[id] = f2bf(W[k * HC + n]);
    }
    int id2 = id - 32768;                   // fc1t[j][q], q in h2 storage order
    if (id2 >= 0 && id2 < 16384) {
        int j = id2 >> 7, q = id2 & 127;
        int L = q >> 1, b = q & 1;
        int kch = 32 * (L >> 4) + (L & 15) + 16 * b;
        float v = (j < 64) ? fc1[kch * 64 + j] : fc1[(128 + kch) * 64 + (j - 64)];
        fc1t[id2] = f2bf(v);
    }
    int id3 = id - (32768 + 16384);
    if (id3 >= 0 && id3 < 128) {
        int jj = id3 & 63;
        float s = gamma[jj] * rsqrtf(var[jj] + 1e-5f);
        scale[id3] = s;
        cc[id3] = (id3 < 64) ? 0.f : (fc1_b[jj] - mean[jj]) * s + beta[jj];
    }
    int id4 = id - (32768 + 16384 + 128);   // fc2m[kk][lane][j]: MFMA B-fragment of fc2
    if (id4 >= 0 && id4 < 1024) {
        int kk = id4 >> 9, rem = id4 & 511;
        int lane = rem >> 3, j = rem & 7;
        int q  = kk * 16 + (lane >> 4) * 4 + (j >> 1);
        int ch = 32 * (q >> 4) + (q & 15) + 16 * (j & 1);
        int col = lane & 15;
        float v = (col < 3) ? fc2_w[ch * 3 + col] : 0.f;
        fc2m[id4] = f2bf(v);
    }
}

// ---------------- CSR build (XCD-partitioned, int4 loads) ----------------
__global__ __launch_bounds__(256) void k_hist(const int* __restrict__ dst,
                                              int* __restrict__ deg) {
    const int g  = blockIdx.x & 7;
    const int bi = blockIdx.x >> 3;
    const int lo = g * NPG, hi = lo + NPG;
    const int4* d4 = (const int4*)dst + bi * 1600;
#pragma unroll 1
    for (int it = 0; it < 7; ++it) {
        int idx = it * 256 + threadIdx.x;
        if (idx < 1600) {
            int4 d = d4[idx];
            if (d.x >= lo && d.x < hi) atomicAdd(&deg[d.x], 1);
            if (d.y >= lo && d.y < hi) atomicAdd(&deg[d.y], 1);
            if (d.z >= lo && d.z < hi) atomicAdd(&deg[d.z], 1);
            if (d.w >= lo && d.w < hi) atomicAdd(&deg[d.w], 1);
        }
    }
}

__global__ void k_scan_part(const int* __restrict__ deg, int* __restrict__ part) {
    __shared__ int sd[256];
    int i = blockIdx.x * 256 + threadIdx.x;
    sd[threadIdx.x] = (i < N_NODES) ? deg[i] : 0;
    __syncthreads();
    for (int off = 128; off > 0; off >>= 1) {
        if (threadIdx.x < off) sd[threadIdx.x] += sd[threadIdx.x + off];
        __syncthreads();
    }
    if (threadIdx.x == 0) part[blockIdx.x] = sd[0];
}

__global__ void k_scan_mid(int* __restrict__ part, int* __restrict__ offs, int nb) {
    __shared__ int sd[256];
    int t = threadIdx.x;
    int v = (t < nb) ? part[t] : 0;
    sd[t] = v;
    __syncthreads();
    for (int off = 1; off < 256; off <<= 1) {
        int u = (t >= off) ? sd[t - off] : 0;
        __syncthreads();
        sd[t] += u;
        __syncthreads();
    }
    if (t < nb) part[t] = sd[t] - v;
    if (t == 255) offs[N_NODES] = sd[255];
}

__global__ void k_scan_final(const int* __restrict__ deg, const int* __restrict__ part,
                             int* __restrict__ offs, int* __restrict__ cur) {
    __shared__ int sd[256];
    int t = threadIdx.x;
    int i = blockIdx.x * 256 + t;
    int v = (i < N_NODES) ? deg[i] : 0;
    sd[t] = v;
    __syncthreads();
    for (int off = 1; off < 256; off <<= 1) {
        int u = (t >= off) ? sd[t - off] : 0;
        __syncthreads();
        sd[t] += u;
        __syncthreads();
    }
    if (i < N_NODES) {
        int o = part[blockIdx.x] + sd[t] - v;
        offs[i] = o;
        cur[i]  = o;
    }
}

// lean scatter: 8B per edge, XCD-partitioned
__global__ __launch_bounds__(256) void k_scatter(const int* __restrict__ src,
                                                 const int* __restrict__ dst,
                                                 int* __restrict__ cur,
                                                 int2* __restrict__ csr2) {
    const int g  = blockIdx.x & 7;
    const int bi = blockIdx.x >> 3;
    const int lo = g * NPG, hi = lo + NPG;
    const int ebase = bi * 6400;
    const int4* d4 = (const int4*)dst + bi * 1600;
    const int4* s4 = (const int4*)src + bi * 1600;
#pragma unroll 1
    for (int it = 0; it < 7; ++it) {
        int idx = it * 256 + threadIdx.x;
        if (idx < 1600) {
            int4 d = d4[idx];
            int4 s = s4[idx];
            int e = ebase + idx * 4;
            if (d.x >= lo && d.x < hi) { int p = atomicAdd(&cur[d.x], 1); csr2[p] = make_int2(s.x, e);     }
            if (d.y >= lo && d.y < hi) { int p = atomicAdd(&cur[d.y], 1); csr2[p] = make_int2(s.y, e + 1); }
            if (d.z >= lo && d.z < hi) { int p = atomicAdd(&cur[d.z], 1); csr2[p] = make_int2(s.z, e + 2); }
            if (d.w >= lo && d.w < hi) { int p = atomicAdd(&cur[d.w], 1); csr2[p] = make_int2(s.w, e + 3); }
        }
    }
}

// ---------------- MFMA GEMM1: LDS-staged x-tile, cf-split waves, fused att ----------------
__global__ __launch_bounds__(256, 4) void k_mfma_xw(const float* __restrict__ x,
                                                    const unsigned short* __restrict__ Wt,
                                                    const float* __restrict__ att_src,
                                                    const float* __restrict__ att_dst,
                                                    unsigned* __restrict__ h_p,
                                                    float* __restrict__ as_,
                                                    float* __restrict__ ad_) {
    __shared__ float xs[16 * 256];        // slot(rl,j) at (rl*64 + (j^rl)), 16B slots
    __shared__ float sAs[16][2], sAd[16][2];
    const int t    = threadIdx.x;
    const int v    = t >> 6;
    const int lane = t & 63;
    const int c16  = lane & 15;
    const int kg   = lane >> 4;
    const int r0   = blockIdx.x * 16;
    if (t < 32) { ((float*)sAs)[t] = 0.f; ((float*)sAd)[t] = 0.f; }

    {
        const float4* xsrc = (const float4*)(x + (size_t)r0 * F_IN);
        float4* xsl = (float4*)xs;
#pragma unroll
        for (int it = 0; it < 4; ++it) {
            int cidx = it * 256 + t;
            int rl = cidx >> 6, j = cidx & 63;
            float4 val = xsrc[cidx];
            xsl[rl * 64 + (j ^ rl)] = val;
        }
    }
    const int cf0 = 2 * v, cf1 = 2 * v + 1;
    bf16x8 wf0[8], wf1[8];
#pragma unroll
    for (int kk = 0; kk < 8; ++kk) {
        wf0[kk] = *(const bf16x8*)(Wt + (size_t)(cf0 * 16 + c16) * 256 + kk * 32 + kg * 8);
        wf1[kk] = *(const bf16x8*)(Wt + (size_t)(cf1 * 16 + c16) * 256 + kk * 32 + kg * 8);
    }
    __syncthreads();

    f32x4 acc0 = {}, acc1 = {};
#pragma unroll
    for (int kk = 0; kk < 8; ++kk) {
        int j0 = kk * 8 + kg * 2;
        float4 a0 = *(const float4*)(xs + (size_t)(c16 * 64 + (j0 ^ c16)) * 4);
        float4 a1 = *(const float4*)(xs + (size_t)(c16 * 64 + ((j0 + 1) ^ c16)) * 4);
        float fv[8] = {a0.x, a0.y, a0.z, a0.w, a1.x, a1.y, a1.z, a1.w};
        bf16x8 ahi, alo;
#pragma unroll
        for (int q = 0; q < 8; ++q) {
            unsigned u = __float_as_uint(fv[q]);
            float hval = __uint_as_float(u & 0xffff0000u);
            float d = fv[q] - hval;
            ahi[q] = (short)(u >> 16);
            alo[q] = (short)(__float_as_uint(d) >> 16);
        }
        acc0 = __builtin_amdgcn_mfma_f32_16x16x32_bf16(alo, wf0[kk], acc0, 0, 0, 0);
        acc0 = __builtin_amdgcn_mfma_f32_16x16x32_bf16(ahi, wf0[kk], acc0, 0, 0, 0);
        acc1 = __builtin_amdgcn_mfma_f32_16x16x32_bf16(alo, wf1[kk], acc1, 0, 0, 0);
        acc1 = __builtin_amdgcn_mfma_f32_16x16x32_bf16(ahi, wf1[kk], acc1, 0, 0, 0);
    }
#pragma unroll
    for (int i = 0; i < 4; ++i) {
        int row = r0 + kg * 4 + i;
        unsigned pu = (unsigned)f2bf(acc0[i]) | ((unsigned)f2bf(acc1[i]) << 16);
        h_p[(size_t)row * 64 + v * 16 + c16] = pu;
    }
    float ws0 = att_src[cf0 * 16 + c16], ws1 = att_src[cf1 * 16 + c16];
    float wd0 = att_dst[cf0 * 16 + c16], wd1 = att_dst[cf1 * 16 + c16];
    float pas[4], pad[4];
#pragma unroll
    for (int i = 0; i < 4; ++i) {
        pas[i] = acc0[i] * ws0 + acc1[i] * ws1;
        pad[i] = acc0[i] * wd0 + acc1[i] * wd1;
    }
#pragma unroll
    for (int m = 1; m < 16; m <<= 1) {
#pragma unroll
        for (int i = 0; i < 4; ++i) {
            pas[i] += __shfl_xor(pas[i], m, 64);
            pad[i] += __shfl_xor(pad[i], m, 64);
        }
    }
    const int head = v >> 1;
    if (c16 == 0) {
#pragma unroll
        for (int i = 0; i < 4; ++i) {
            atomicAdd(&sAs[kg * 4 + i][head], pas[i]);
            atomicAdd(&sAd[kg * 4 + i][head], pad[i]);
        }
    }
    __syncthreads();
    if (t < 32) {
        int row = t >> 1, hd = t & 1;
        as_[(r0 + row) * 2 + hd] = sAs[row][hd];
        ad_[(r0 + row) * 2 + hd] = sAd[row][hd];
    }
}

// ---------------- k_wcalc: edge-order softmax weights (coalesced) ----------------
__global__ __launch_bounds__(256) void k_wcalc(const int* __restrict__ src,
                                               const int* __restrict__ dst,
                                               const float* __restrict__ as_,
                                               const float* __restrict__ ad_,
                                               float2* __restrict__ wtab) {
    int e = blockIdx.x * 256 + threadIdx.x;
    int s = src[e], d = dst[e];
    float2 a = ((const float2*)as_)[s];
    float2 b = ((const float2*)ad_)[d];
    float l0 = a.x + b.x, l1 = a.y + b.y;
    l0 = fmaxf(l0, 0.2f * l0);
    l1 = fmaxf(l1, 0.2f * l1);
    wtab[e] = make_float2(__expf(l0), __expf(l1));
}

// ---------------- k_agg: half-wave, 4 gathers in flight, wtab weights ----------------
__global__ __launch_bounds__(256) void k_agg(const unsigned* __restrict__ h_p,
                                             const float* __restrict__ as_,
                                             const float* __restrict__ ad_,
                                             const int* __restrict__ offs,
                                             const int2* __restrict__ csr2,
                                             const float2* __restrict__ wtab,
                                             const float* __restrict__ conv_bias,
                                             unsigned* __restrict__ h2_p) {
    const int n    = blockIdx.x * 4 + (threadIdx.x >> 6);
    const int lane = threadIdx.x & 63;
    const int L    = lane & 31;
    const int half = lane >> 5;
    const int hd   = L >> 4;
    const uint2* hrows = (const uint2*)h_p;
    float a0 = 0.f, a1 = 0.f, a2 = 0.f, a3 = 0.f, accw = 0.f;
    const int beg = offs[n], end = offs[n + 1];
    int i = beg + half;
    for (; i + 6 < end; i += 8) {        // 8 edges/wave-iter, 4 gathers per half in flight
        int2 c0 = csr2[i];
        int2 c1 = csr2[i + 2];
        int2 c2 = csr2[i + 4];
        int2 c3 = csr2[i + 6];
        uint2 u0 = hrows[(unsigned)(c0.x * 32 + L)];
        uint2 u1 = hrows[(unsigned)(c1.x * 32 + L)];
        uint2 u2 = hrows[(unsigned)(c2.x * 32 + L)];
        uint2 u3 = hrows[(unsigned)(c3.x * 32 + L)];
        float2 wv0 = wtab[c0.y];
        float2 wv1 = wtab[c1.y];
        float2 wv2 = wtab[c2.y];
        float2 wv3 = wtab[c3.y];
        float w0 = hd ? wv0.y : wv0.x;
        float w1 = hd ? wv1.y : wv1.x;
        float w2 = hd ? wv2.y : wv2.x;
        float w3 = hd ? wv3.y : wv3.x;
        float2 f0a = bf2(u0.x), f0b = bf2(u0.y);
        float2 f1a = bf2(u1.x), f1b = bf2(u1.y);
        float2 f2a = bf2(u2.x), f2b = bf2(u2.y);
        float2 f3a = bf2(u3.x), f3b = bf2(u3.y);
        a0 += w0 * f0a.x + w1 * f1a.x + w2 * f2a.x + w3 * f3a.x;
        a1 += w0 * f0a.y + w1 * f1a.y + w2 * f2a.y + w3 * f3a.y;
        a2 += w0 * f0b.x + w1 * f1b.x + w2 * f2b.x + w3 * f3b.x;
        a3 += w0 * f0b.y + w1 * f1b.y + w2 * f2b.y + w3 * f3b.y;
        accw += w0 + w1 + w2 + w3;
    }
    for (; i < end; i += 2) {
        int2 c0 = csr2[i];
        uint2 u0 = hrows[(unsigned)(c0.x * 32 + L)];
        float2 wv0 = wtab[c0.y];
        float w0 = hd ? wv0.y : wv0.x;
        float2 f0a = bf2(u0.x), f0b = bf2(u0.y);
        a0 += w0 * f0a.x;
        a1 += w0 * f0a.y;
        a2 += w0 * f0b.x;
        a3 += w0 * f0b.y;
        accw += w0;
    }
    a0 += __shfl_xor(a0, 32, 64);
    a1 += __shfl_xor(a1, 32, 64);
    a2 += __shfl_xor(a2, 32, 64);
    a3 += __shfl_xor(a3, 32, 64);
    accw += __shfl_xor(accw, 32, 64);
    if (half == 0) {
        float es = as_[n * 2 + hd] + ad_[n * 2 + hd];   // self-loop
        es = fmaxf(es, 0.2f * es);
        float wsl = __expf(es);
        uint2 un = hrows[(unsigned)(n * 32 + L)];
        float2 na = bf2(un.x), nb = bf2(un.y);
        a0 += wsl * na.x; a1 += wsl * na.y; a2 += wsl * nb.x; a3 += wsl * nb.y;
        accw += wsl;
        const int q0 = 2 * L, q1 = 2 * L + 1;
        const int c00 = 32 * (q0 >> 4) + (q0 & 15);
        const int c01 = 32 * (q1 >> 4) + (q1 & 15);
        float rinv = 1.f / accw;
        float o0 = a0 * rinv + conv_bias[c00];
        float o1 = a1 * rinv + conv_bias[c00 + 16];
        float o2 = a2 * rinv + conv_bias[c01];
        float o3 = a3 * rinv + conv_bias[c01 + 16];
        o0 = fmaxf(o0, 0.01f * o0);
        o1 = fmaxf(o1, 0.01f * o1);
        o2 = fmaxf(o2, 0.01f * o2);
        o3 = fmaxf(o3, 0.01f * o3);
        unsigned p0 = (unsigned)f2bf(o0) | ((unsigned)f2bf(o1) << 16);
        unsigned p1 = (unsigned)f2bf(o2) | ((unsigned)f2bf(o3) << 16);
        ((uint2*)h2_p)[(unsigned)(n * 32 + L)] = make_uint2(p0, p1);
    }
}

// ---------------- MFMA GEMM2: ab = BN-folded h2 @ fc1t^T ----------------
__global__ __launch_bounds__(256) void k_mfma_uv(const unsigned short* __restrict__ h2,
                                                 const unsigned short* __restrict__ fc1t,
                                                 const float* __restrict__ scale,
                                                 const float* __restrict__ cc,
                                                 unsigned* __restrict__ ab_p) {
    const int w = blockIdx.x * 4 + (threadIdx.x >> 6);
    if (w >= N_NODES / 16) return;
    const int lane = threadIdx.x & 63;
    const int c16  = lane & 15;
    const int kg   = lane >> 4;
    const int r0   = w * 16;
    const unsigned short* arow = h2 + (size_t)(r0 + c16) * HC + kg * 8;
    bf16x8 af[4];
#pragma unroll
    for (int kk = 0; kk < 4; ++kk) af[kk] = *(const bf16x8*)(arow + kk * 32);
    f32x4 acc[8] = {};
#pragma unroll
    for (int kk = 0; kk < 4; ++kk) {
        const unsigned short* wp = fc1t + c16 * HC + kk * 32 + kg * 8;
#pragma unroll
        for (int cf = 0; cf < 8; ++cf) {
            bf16x8 b = *(const bf16x8*)(wp + cf * 16 * HC);
            acc[cf] = __builtin_amdgcn_mfma_f32_16x16x32_bf16(af[kk], b, acc[cf], 0, 0, 0);
        }
    }
#pragma unroll
    for (int cf = 0; cf < 8; cf += 2) {
        int j0 = cf * 16 + c16, j1 = j0 + 16;
        float s0 = scale[j0], s1 = scale[j1];
        float q0 = cc[j0],    q1 = cc[j1];
#pragma unroll
        for (int i = 0; i < 4; ++i) {
            int row = r0 + kg * 4 + i;
            unsigned pu = (unsigned)f2bf(acc[cf][i] * s0 + q0)
                        | ((unsigned)f2bf(acc[cf + 1][i] * s1 + q1) << 16);
            ab_p[(size_t)row * 64 + (cf >> 1) * 16 + c16] = pu;
        }
    }
}

// ---------------- k_edge: MFMA tail — 16 edges/wave, A=lrelu(a+b), B=fc2 ----------------
__device__ __forceinline__ void mk_afrag(uint4 ua, const float* bb, bf16x8& ap) {
    float2 t; float z;
    t = bf2(ua.x);
    z = t.x + bb[0]; z = fmaxf(z, 0.01f * z); ap[0] = f2bf_s(z);
    z = t.y + bb[1]; z = fmaxf(z, 0.01f * z); ap[1] = f2bf_s(z);
    t = bf2(ua.y);
    z = t.x + bb[2]; z = fmaxf(z, 0.01f * z); ap[2] = f2bf_s(z);
    z = t.y + bb[3]; z = fmaxf(z, 0.01f * z); ap[3] = f2bf_s(z);
    t = bf2(ua.z);
    z = t.x + bb[4]; z = fmaxf(z, 0.01f * z); ap[4] = f2bf_s(z);
    z = t.y + bb[5]; z = fmaxf(z, 0.01f * z); ap[5] = f2bf_s(z);
    t = bf2(ua.w);
    z = t.x + bb[6]; z = fmaxf(z, 0.01f * z); ap[6] = f2bf_s(z);
    z = t.y + bb[7]; z = fmaxf(z, 0.01f * z); ap[7] = f2bf_s(z);
}

__global__ __launch_bounds__(256) void k_edge(const int* __restrict__ offs,
                                              const int2* __restrict__ csr2,
                                              const unsigned* __restrict__ ab_p,
                                              const unsigned short* __restrict__ fc2m,
                                              const float* __restrict__ fc2_b,
                                              float* __restrict__ out) {
    const int n    = blockIdx.x * 4 + (threadIdx.x >> 6);
    const int lane = threadIdx.x & 63;
    const int c16  = lane & 15;
    const int kg   = lane >> 4;
    bf16x8 bfr0 = *(const bf16x8*)(fc2m + (size_t)lane * 8);
    bf16x8 bfr1 = *(const bf16x8*)(fc2m + (size_t)(64 + lane) * 8);
    const uint4* abv = (const uint4*)ab_p;
    // dst B-half (hoisted): words n*16+8+kk*4+kg
    uint4 ub0 = abv[(unsigned)(n * 16 + 8 + kg)];
    uint4 ub1 = abv[(unsigned)(n * 16 + 12 + kg)];
    float bb0[8], bb1[8];
    {
        float2 t;
        t = bf2(ub0.x); bb0[0] = t.x; bb0[1] = t.y;
        t = bf2(ub0.y); bb0[2] = t.x; bb0[3] = t.y;
        t = bf2(ub0.z); bb0[4] = t.x; bb0[5] = t.y;
        t = bf2(ub0.w); bb0[6] = t.x; bb0[7] = t.y;
        t = bf2(ub1.x); bb1[0] = t.x; bb1[1] = t.y;
        t = bf2(ub1.y); bb1[2] = t.x; bb1[3] = t.y;
        t = bf2(ub1.z); bb1[4] = t.x; bb1[5] = t.y;
        t = bf2(ub1.w); bb1[6] = t.x; bb1[7] = t.y;
    }
    const float ob = (c16 < 3) ? fc2_b[c16] : 0.f;
    const int beg = offs[n], end = offs[n + 1];
    for (int base = beg; base < end; base += 16) {
        int slot = base + c16;
        int2 ce = (slot < end) ? csr2[slot] : make_int2(0, 0);
        uint4 ua0 = abv[(unsigned)(ce.x * 16 + kg)];
        uint4 ua1 = abv[(unsigned)(ce.x * 16 + 4 + kg)];
        bf16x8 ap0, ap1;
        mk_afrag(ua0, bb0, ap0);
        mk_afrag(ua1, bb1, ap1);
        f32x4 acc = {};
        acc = __builtin_amdgcn_mfma_f32_16x16x32_bf16(ap0, bfr0, acc, 0, 0, 0);
        acc = __builtin_amdgcn_mfma_f32_16x16x32_bf16(ap1, bfr1, acc, 0, 0, 0);
#pragma unroll
        for (int i = 0; i < 4; ++i) {
            int eid = __shfl(ce.y, kg * 4 + i, 64);
            if (c16 < 3 && (base + kg * 4 + i) < end)
                out[(size_t)eid * 3 + c16] = acc[i] + ob;
        }
    }
}

extern "C" void kernel_launch(void* const* d_in, const int* in_sizes, int n_in,
                              void* d_out, int out_size, void* d_ws, size_t ws_size,
                              hipStream_t stream) {
    const float* x        = (const float*)d_in[0];
    const int*   ei       = (const int*)d_in[1];
    const float* W        = (const float*)d_in[2];
    const float* att_src  = (const float*)d_in[3];
    const float* att_dst  = (const float*)d_in[4];
    const float* conv_b   = (const float*)d_in[5];
    const float* fc1_w    = (const float*)d_in[6];
    const float* fc1_b    = (const float*)d_in[7];
    const float* gamma    = (const float*)d_in[8];
    const float* beta     = (const float*)d_in[9];
    const float* mean     = (const float*)d_in[10];
    const float* var      = (const float*)d_in[11];
    const float* fc2_w    = (const float*)d_in[12];
    const float* fc2_b    = (const float*)d_in[13];
    float*       out      = (float*)d_out;
    char*        ws       = (char*)d_ws;

    const int* src = ei;
    const int* dst = ei + N_EDGES;

    unsigned*       h_p   = (unsigned*)(ws + OFF_HBF);
    unsigned*       h2_p  = (unsigned*)(ws + OFF_H2);
    unsigned*       ab_p  = (unsigned*)(ws + OFF_AB);
    float*          as_   = (float*)(ws + OFF_AS);
    float*          ad_   = (float*)(ws + OFF_AD);
    int*            offs  = (int*)(ws + OFF_OFFS);
    int*            deg   = (int*)(ws + OFF_DEG);
    int*            cur   = (int*)(ws + OFF_CUR);
    int*            part  = (int*)(ws + OFF_PART);
    int2*           csr2  = (int2*)(ws + OFF_CSR2);
    float2*         wtab  = (float2*)(ws + OFF_WTAB);
    unsigned short* Wt    = (unsigned short*)(ws + OFF_WT);
    unsigned short* fc1t  = (unsigned short*)(ws + OFF_FC1T);
    float*          scale = (float*)(ws + OFF_SCALE);
    float*          cc    = (float*)(ws + OFF_CC);
    unsigned short* fc2m  = (unsigned short*)(ws + OFF_FC2M);

    // prep (tiny; also zeroes deg)
    k_prep<<<235, 256, 0, stream>>>(W, fc1_w, fc1_b, gamma, beta, mean, var, fc2_w,
                                    Wt, fc1t, scale, cc, fc2m, deg);

    // CSR build
    k_hist      <<<1000, 256, 0, stream>>>(dst, deg);
    k_scan_part <<<(N_NODES + 255) / 256, 256, 0, stream>>>(deg, part);
    k_scan_mid  <<<1, 256, 0, stream>>>(part, offs, (N_NODES + 255) / 256);
    k_scan_final<<<(N_NODES + 255) / 256, 256, 0, stream>>>(deg, part, offs, cur);
    k_scatter   <<<1000, 256, 0, stream>>>(src, dst, cur, csr2);

    // node pipeline
    k_mfma_xw<<<N_NODES / 16, 256, 0, stream>>>(x, Wt, att_src, att_dst, h_p, as_, ad_);
    k_wcalc  <<<N_EDGES / 256, 256, 0, stream>>>(src, dst, as_, ad_, wtab);
    k_agg    <<<N_NODES / 4, 256, 0, stream>>>(h_p, as_, ad_, offs, csr2, wtab, conv_b, h2_p);
    k_mfma_uv<<<(N_NODES / 16 + 3) / 4, 256, 0, stream>>>((const unsigned short*)h2_p, fc1t, scale, cc, ab_p);

    // edge tail (MFMA)
    k_edge<<<N_NODES / 4, 256, 0, stream>>>(offs, csr2, ab_p, fc2m, fc2_b, out);
}

// Round 12
// 209.960 us; speedup vs baseline: 1.0906x; 1.0906x over previous
//
#include <hip/hip_runtime.h>
#include <hip/hip_bf16.h>

#define N_NODES 50000
#define N_EDGES 800000
#define F_IN    256
#define C_DIM   64
#define HC      128   // H*C
#define NPG     6250  // nodes per XCD group (N/8)

typedef __attribute__((ext_vector_type(8))) short bf16x8;
typedef __attribute__((ext_vector_type(4))) float f32x4;

// ---------------- workspace layout (bytes) ----------------
static constexpr size_t OFF_HBF   = 0;           // u32  h packed  [N][64] = 12.8 MB
static constexpr size_t OFF_H2    = 12800000;    // u32  h2 packed [N][64] = 12.8 MB
static constexpr size_t OFF_AB    = 25600000;    // u32  ab packed [N][64] = 12.8 MB
static constexpr size_t OFF_AS    = 38400000;    // f32 [N][2]
static constexpr size_t OFF_AD    = 38800000;
static constexpr size_t OFF_OFFS  = 39200000;    // i32 N+1
static constexpr size_t OFF_DEG   = 39400064;
static constexpr size_t OFF_CUR   = 39600064;
static constexpr size_t OFF_PART  = 39800064;
static constexpr size_t OFF_CSR2  = 39801088;    // int2 [E] (src,eid) = 6.4 MB
static constexpr size_t OFF_WT    = 46201088;    // bf16 Wt   [128][256] = 64 KB
static constexpr size_t OFF_FC1T  = 46266624;    // bf16 fc1t [128][128] = 32 KB
static constexpr size_t OFF_SCALE = 46299392;    // f32 [128]
static constexpr size_t OFF_CC    = 46299904;    // f32 [128]
static constexpr size_t OFF_FC2M  = 46300416;    // bf16 fc2m [2][64][8] = 2 KB

__device__ __forceinline__ float2 bf2(unsigned u) {
    float2 r;
    r.x = __uint_as_float(u << 16);
    r.y = __uint_as_float(u & 0xffff0000u);
    return r;
}
__device__ __forceinline__ unsigned short f2bf(float f) {
    unsigned u = __float_as_uint(f);
    return (unsigned short)((u + 0x7fffu + ((u >> 16) & 1u)) >> 16);  // RNE
}
__device__ __forceinline__ short f2bf_s(float f) {
    __hip_bfloat16 h = __float2bfloat16(f);
    return *reinterpret_cast<short*>(&h);
}
// packed-channel mapping: word q (0..63) of a row holds channels (c0(q), c0(q)+16),
// c0(q) = 32*(q>>4) + (q&15)

// ---------------- prep: Wt, fc1t, fc2m, BN scale/cc, deg zero ----------------
__global__ __launch_bounds__(256) void k_prep(const float* __restrict__ W,
                                              const float* __restrict__ fc1,
                                              const float* __restrict__ fc1_b,
                                              const float* __restrict__ gamma,
                                              const float* __restrict__ beta,
                                              const float* __restrict__ mean,
                                              const float* __restrict__ var,
                                              const float* __restrict__ fc2_w,
                                              unsigned short* __restrict__ Wt,
                                              unsigned short* __restrict__ fc1t,
                                              float* __restrict__ scale,
                                              float* __restrict__ cc,
                                              unsigned short* __restrict__ fc2m,
                                              int* __restrict__ deg) {
    int id = blockIdx.x * 256 + threadIdx.x;
    if (id < N_NODES) deg[id] = 0;
    if (id < 32768) {                       // Wt[n][k] = bf16(W[k][n])
        int n = id >> 8, k = id & 255;
        Wt[id] = f2bf(W[k * HC + n]);
    }
    int id2 = id - 32768;                   // fc1t[j][q], q in h2 storage order
    if (id2 >= 0 && id2 < 16384) {
        int j = id2 >> 7, q = id2 & 127;
        int L = q >> 1, b = q & 1;
        int kch = 32 * (L >> 4) + (L & 15) + 16 * b;
        float v = (j < 64) ? fc1[kch * 64 + j] : fc1[(128 + kch) * 64 + (j - 64)];
        fc1t[id2] = f2bf(v);
    }
    int id3 = id - (32768 + 16384);
    if (id3 >= 0 && id3 < 128) {
        int jj = id3 & 63;
        float s = gamma[jj] * rsqrtf(var[jj] + 1e-5f);
        scale[id3] = s;
        cc[id3] = (id3 < 64) ? 0.f : (fc1_b[jj] - mean[jj]) * s + beta[jj];
    }
    int id4 = id - (32768 + 16384 + 128);   // fc2m[kk][lane][j]: MFMA B-fragment of fc2
    if (id4 >= 0 && id4 < 1024) {
        int kk = id4 >> 9, rem = id4 & 511;
        int lane = rem >> 3, j = rem & 7;
        int q  = kk * 16 + (lane >> 4) * 4 + (j >> 1);
        int ch = 32 * (q >> 4) + (q & 15) + 16 * (j & 1);
        int col = lane & 15;
        float v = (col < 3) ? fc2_w[ch * 3 + col] : 0.f;
        fc2m[id4] = f2bf(v);
    }
}

// ---------------- CSR build (XCD-partitioned, int4 loads) ----------------
__global__ __launch_bounds__(256) void k_hist(const int* __restrict__ dst,
                                              int* __restrict__ deg) {
    const int g  = blockIdx.x & 7;
    const int bi = blockIdx.x >> 3;
    const int lo = g * NPG, hi = lo + NPG;
    const int4* d4 = (const int4*)dst + bi * 1600;
#pragma unroll 1
    for (int it = 0; it < 7; ++it) {
        int idx = it * 256 + threadIdx.x;
        if (idx < 1600) {
            int4 d = d4[idx];
            if (d.x >= lo && d.x < hi) atomicAdd(&deg[d.x], 1);
            if (d.y >= lo && d.y < hi) atomicAdd(&deg[d.y], 1);
            if (d.z >= lo && d.z < hi) atomicAdd(&deg[d.z], 1);
            if (d.w >= lo && d.w < hi) atomicAdd(&deg[d.w], 1);
        }
    }
}

__global__ void k_scan_part(const int* __restrict__ deg, int* __restrict__ part) {
    __shared__ int sd[256];
    int i = blockIdx.x * 256 + threadIdx.x;
    sd[threadIdx.x] = (i < N_NODES) ? deg[i] : 0;
    __syncthreads();
    for (int off = 128; off > 0; off >>= 1) {
        if (threadIdx.x < off) sd[threadIdx.x] += sd[threadIdx.x + off];
        __syncthreads();
    }
    if (threadIdx.x == 0) part[blockIdx.x] = sd[0];
}

__global__ void k_scan_mid(int* __restrict__ part, int* __restrict__ offs, int nb) {
    __shared__ int sd[256];
    int t = threadIdx.x;
    int v = (t < nb) ? part[t] : 0;
    sd[t] = v;
    __syncthreads();
    for (int off = 1; off < 256; off <<= 1) {
        int u = (t >= off) ? sd[t - off] : 0;
        __syncthreads();
        sd[t] += u;
        __syncthreads();
    }
    if (t < nb) part[t] = sd[t] - v;
    if (t == 255) offs[N_NODES] = sd[255];
}

__global__ void k_scan_final(const int* __restrict__ deg, const int* __restrict__ part,
                             int* __restrict__ offs, int* __restrict__ cur) {
    __shared__ int sd[256];
    int t = threadIdx.x;
    int i = blockIdx.x * 256 + t;
    int v = (i < N_NODES) ? deg[i] : 0;
    sd[t] = v;
    __syncthreads();
    for (int off = 1; off < 256; off <<= 1) {
        int u = (t >= off) ? sd[t - off] : 0;
        __syncthreads();
        sd[t] += u;
        __syncthreads();
    }
    if (i < N_NODES) {
        int o = part[blockIdx.x] + sd[t] - v;
        offs[i] = o;
        cur[i]  = o;
    }
}

// lean scatter: 8B per edge, XCD-partitioned
__global__ __launch_bounds__(256) void k_scatter(const int* __restrict__ src,
                                                 const int* __restrict__ dst,
                                                 int* __restrict__ cur,
                                                 int2* __restrict__ csr2) {
    const int g  = blockIdx.x & 7;
    const int bi = blockIdx.x >> 3;
    const int lo = g * NPG, hi = lo + NPG;
    const int ebase = bi * 6400;
    const int4* d4 = (const int4*)dst + bi * 1600;
    const int4* s4 = (const int4*)src + bi * 1600;
#pragma unroll 1
    for (int it = 0; it < 7; ++it) {
        int idx = it * 256 + threadIdx.x;
        if (idx < 1600) {
            int4 d = d4[idx];
            int4 s = s4[idx];
            int e = ebase + idx * 4;
            if (d.x >= lo && d.x < hi) { int p = atomicAdd(&cur[d.x], 1); csr2[p] = make_int2(s.x, e);     }
            if (d.y >= lo && d.y < hi) { int p = atomicAdd(&cur[d.y], 1); csr2[p] = make_int2(s.y, e + 1); }
            if (d.z >= lo && d.z < hi) { int p = atomicAdd(&cur[d.z], 1); csr2[p] = make_int2(s.z, e + 2); }
            if (d.w >= lo && d.w < hi) { int p = atomicAdd(&cur[d.w], 1); csr2[p] = make_int2(s.w, e + 3); }
        }
    }
}

// ---------------- MFMA GEMM1: LDS-staged x-tile, cf-split waves, fused att ----------------
__global__ __launch_bounds__(256, 4) void k_mfma_xw(const float* __restrict__ x,
                                                    const unsigned short* __restrict__ Wt,
                                                    const float* __restrict__ att_src,
                                                    const float* __restrict__ att_dst,
                                                    unsigned* __restrict__ h_p,
                                                    float* __restrict__ as_,
                                                    float* __restrict__ ad_) {
    __shared__ float xs[16 * 256];        // slot(rl,j) at (rl*64 + (j^rl)), 16B slots
    __shared__ float sAs[16][2], sAd[16][2];
    const int t    = threadIdx.x;
    const int v    = t >> 6;
    const int lane = t & 63;
    const int c16  = lane & 15;
    const int kg   = lane >> 4;
    const int r0   = blockIdx.x * 16;
    if (t < 32) { ((float*)sAs)[t] = 0.f; ((float*)sAd)[t] = 0.f; }

    {
        const float4* xsrc = (const float4*)(x + (size_t)r0 * F_IN);
        float4* xsl = (float4*)xs;
#pragma unroll
        for (int it = 0; it < 4; ++it) {
            int cidx = it * 256 + t;
            int rl = cidx >> 6, j = cidx & 63;
            float4 val = xsrc[cidx];
            xsl[rl * 64 + (j ^ rl)] = val;
        }
    }
    const int cf0 = 2 * v, cf1 = 2 * v + 1;
    bf16x8 wf0[8], wf1[8];
#pragma unroll
    for (int kk = 0; kk < 8; ++kk) {
        wf0[kk] = *(const bf16x8*)(Wt + (size_t)(cf0 * 16 + c16) * 256 + kk * 32 + kg * 8);
        wf1[kk] = *(const bf16x8*)(Wt + (size_t)(cf1 * 16 + c16) * 256 + kk * 32 + kg * 8);
    }
    __syncthreads();

    f32x4 acc0 = {}, acc1 = {};
#pragma unroll
    for (int kk = 0; kk < 8; ++kk) {
        int j0 = kk * 8 + kg * 2;
        float4 a0 = *(const float4*)(xs + (size_t)(c16 * 64 + (j0 ^ c16)) * 4);
        float4 a1 = *(const float4*)(xs + (size_t)(c16 * 64 + ((j0 + 1) ^ c16)) * 4);
        float fv[8] = {a0.x, a0.y, a0.z, a0.w, a1.x, a1.y, a1.z, a1.w};
        bf16x8 ahi, alo;
#pragma unroll
        for (int q = 0; q < 8; ++q) {
            unsigned u = __float_as_uint(fv[q]);
            float hval = __uint_as_float(u & 0xffff0000u);
            float d = fv[q] - hval;
            ahi[q] = (short)(u >> 16);
            alo[q] = (short)(__float_as_uint(d) >> 16);
        }
        acc0 = __builtin_amdgcn_mfma_f32_16x16x32_bf16(alo, wf0[kk], acc0, 0, 0, 0);
        acc0 = __builtin_amdgcn_mfma_f32_16x16x32_bf16(ahi, wf0[kk], acc0, 0, 0, 0);
        acc1 = __builtin_amdgcn_mfma_f32_16x16x32_bf16(alo, wf1[kk], acc1, 0, 0, 0);
        acc1 = __builtin_amdgcn_mfma_f32_16x16x32_bf16(ahi, wf1[kk], acc1, 0, 0, 0);
    }
#pragma unroll
    for (int i = 0; i < 4; ++i) {
        int row = r0 + kg * 4 + i;
        unsigned pu = (unsigned)f2bf(acc0[i]) | ((unsigned)f2bf(acc1[i]) << 16);
        h_p[(size_t)row * 64 + v * 16 + c16] = pu;
    }
    float ws0 = att_src[cf0 * 16 + c16], ws1 = att_src[cf1 * 16 + c16];
    float wd0 = att_dst[cf0 * 16 + c16], wd1 = att_dst[cf1 * 16 + c16];
    float pas[4], pad[4];
#pragma unroll
    for (int i = 0; i < 4; ++i) {
        pas[i] = acc0[i] * ws0 + acc1[i] * ws1;
        pad[i] = acc0[i] * wd0 + acc1[i] * wd1;
    }
#pragma unroll
    for (int m = 1; m < 16; m <<= 1) {
#pragma unroll
        for (int i = 0; i < 4; ++i) {
            pas[i] += __shfl_xor(pas[i], m, 64);
            pad[i] += __shfl_xor(pad[i], m, 64);
        }
    }
    const int head = v >> 1;
    if (c16 == 0) {
#pragma unroll
        for (int i = 0; i < 4; ++i) {
            atomicAdd(&sAs[kg * 4 + i][head], pas[i]);
            atomicAdd(&sAd[kg * 4 + i][head], pad[i]);
        }
    }
    __syncthreads();
    if (t < 32) {
        int row = t >> 1, hd = t & 1;
        as_[(r0 + row) * 2 + hd] = sAs[row][hd];
        ad_[(r0 + row) * 2 + hd] = sAd[row][hd];
    }
}

// ---------------- k_agg: half-wave, 4 gathers in flight, inline softmax w ----------------
__global__ __launch_bounds__(256) void k_agg(const unsigned* __restrict__ h_p,
                                             const float* __restrict__ as_,
                                             const float* __restrict__ ad_,
                                             const int* __restrict__ offs,
                                             const int2* __restrict__ csr2,
                                             const float* __restrict__ conv_bias,
                                             unsigned* __restrict__ h2_p) {
    const int n    = blockIdx.x * 4 + (threadIdx.x >> 6);
    const int lane = threadIdx.x & 63;
    const int L    = lane & 31;
    const int half = lane >> 5;
    const int hd   = L >> 4;
    const float adn = ad_[n * 2 + hd];
    const uint2* hrows = (const uint2*)h_p;
    float a0 = 0.f, a1 = 0.f, a2 = 0.f, a3 = 0.f, accw = 0.f;
    const int beg = offs[n], end = offs[n + 1];
    int i = beg + half;
    for (; i + 6 < end; i += 8) {        // 8 edges/wave-iter, 4 gathers per half in flight
        int s0 = csr2[i].x;
        int s1 = csr2[i + 2].x;
        int s2 = csr2[i + 4].x;
        int s3 = csr2[i + 6].x;
        uint2 u0 = hrows[(unsigned)(s0 * 32 + L)];
        uint2 u1 = hrows[(unsigned)(s1 * 32 + L)];
        uint2 u2 = hrows[(unsigned)(s2 * 32 + L)];
        uint2 u3 = hrows[(unsigned)(s3 * 32 + L)];
        float l0 = as_[s0 * 2 + hd] + adn;
        float l1 = as_[s1 * 2 + hd] + adn;
        float l2 = as_[s2 * 2 + hd] + adn;
        float l3 = as_[s3 * 2 + hd] + adn;
        l0 = fmaxf(l0, 0.2f * l0); l1 = fmaxf(l1, 0.2f * l1);
        l2 = fmaxf(l2, 0.2f * l2); l3 = fmaxf(l3, 0.2f * l3);
        float w0 = __expf(l0), w1 = __expf(l1), w2 = __expf(l2), w3 = __expf(l3);
        float2 f0a = bf2(u0.x), f0b = bf2(u0.y);
        float2 f1a = bf2(u1.x), f1b = bf2(u1.y);
        float2 f2a = bf2(u2.x), f2b = bf2(u2.y);
        float2 f3a = bf2(u3.x), f3b = bf2(u3.y);
        a0 += w0 * f0a.x + w1 * f1a.x + w2 * f2a.x + w3 * f3a.x;
        a1 += w0 * f0a.y + w1 * f1a.y + w2 * f2a.y + w3 * f3a.y;
        a2 += w0 * f0b.x + w1 * f1b.x + w2 * f2b.x + w3 * f3b.x;
        a3 += w0 * f0b.y + w1 * f1b.y + w2 * f2b.y + w3 * f3b.y;
        accw += w0 + w1 + w2 + w3;
    }
    for (; i < end; i += 2) {
        int s0 = csr2[i].x;
        float l0 = as_[s0 * 2 + hd] + adn;
        uint2 u0 = hrows[(unsigned)(s0 * 32 + L)];
        l0 = fmaxf(l0, 0.2f * l0);
        float w0 = __expf(l0);
        float2 f0a = bf2(u0.x), f0b = bf2(u0.y);
        a0 += w0 * f0a.x;
        a1 += w0 * f0a.y;
        a2 += w0 * f0b.x;
        a3 += w0 * f0b.y;
        accw += w0;
    }
    a0 += __shfl_xor(a0, 32, 64);
    a1 += __shfl_xor(a1, 32, 64);
    a2 += __shfl_xor(a2, 32, 64);
    a3 += __shfl_xor(a3, 32, 64);
    accw += __shfl_xor(accw, 32, 64);
    if (half == 0) {
        float es = as_[n * 2 + hd] + adn;   // self-loop
        es = fmaxf(es, 0.2f * es);
        float wsl = __expf(es);
        uint2 un = hrows[(unsigned)(n * 32 + L)];
        float2 na = bf2(un.x), nb = bf2(un.y);
        a0 += wsl * na.x; a1 += wsl * na.y; a2 += wsl * nb.x; a3 += wsl * nb.y;
        accw += wsl;
        const int q0 = 2 * L, q1 = 2 * L + 1;
        const int c00 = 32 * (q0 >> 4) + (q0 & 15);
        const int c01 = 32 * (q1 >> 4) + (q1 & 15);
        float rinv = 1.f / accw;
        float o0 = a0 * rinv + conv_bias[c00];
        float o1 = a1 * rinv + conv_bias[c00 + 16];
        float o2 = a2 * rinv + conv_bias[c01];
        float o3 = a3 * rinv + conv_bias[c01 + 16];
        o0 = fmaxf(o0, 0.01f * o0);
        o1 = fmaxf(o1, 0.01f * o1);
        o2 = fmaxf(o2, 0.01f * o2);
        o3 = fmaxf(o3, 0.01f * o3);
        unsigned p0 = (unsigned)f2bf(o0) | ((unsigned)f2bf(o1) << 16);
        unsigned p1 = (unsigned)f2bf(o2) | ((unsigned)f2bf(o3) << 16);
        ((uint2*)h2_p)[(unsigned)(n * 32 + L)] = make_uint2(p0, p1);
    }
}

// ---------------- MFMA GEMM2: ab = BN-folded h2 @ fc1t^T ----------------
__global__ __launch_bounds__(256) void k_mfma_uv(const unsigned short* __restrict__ h2,
                                                 const unsigned short* __restrict__ fc1t,
                                                 const float* __restrict__ scale,
                                                 const float* __restrict__ cc,
                                                 unsigned* __restrict__ ab_p) {
    const int w = blockIdx.x * 4 + (threadIdx.x >> 6);
    if (w >= N_NODES / 16) return;
    const int lane = threadIdx.x & 63;
    const int c16  = lane & 15;
    const int kg   = lane >> 4;
    const int r0   = w * 16;
    const unsigned short* arow = h2 + (size_t)(r0 + c16) * HC + kg * 8;
    bf16x8 af[4];
#pragma unroll
    for (int kk = 0; kk < 4; ++kk) af[kk] = *(const bf16x8*)(arow + kk * 32);
    f32x4 acc[8] = {};
#pragma unroll
    for (int kk = 0; kk < 4; ++kk) {
        const unsigned short* wp = fc1t + c16 * HC + kk * 32 + kg * 8;
#pragma unroll
        for (int cf = 0; cf < 8; ++cf) {
            bf16x8 b = *(const bf16x8*)(wp + cf * 16 * HC);
            acc[cf] = __builtin_amdgcn_mfma_f32_16x16x32_bf16(af[kk], b, acc[cf], 0, 0, 0);
        }
    }
#pragma unroll
    for (int cf = 0; cf < 8; cf += 2) {
        int j0 = cf * 16 + c16, j1 = j0 + 16;
        float s0 = scale[j0], s1 = scale[j1];
        float q0 = cc[j0],    q1 = cc[j1];
#pragma unroll
        for (int i = 0; i < 4; ++i) {
            int row = r0 + kg * 4 + i;
            unsigned pu = (unsigned)f2bf(acc[cf][i] * s0 + q0)
                        | ((unsigned)f2bf(acc[cf + 1][i] * s1 + q1) << 16);
            ab_p[(size_t)row * 64 + (cf >> 1) * 16 + c16] = pu;
        }
    }
}

// ---------------- k_edge: MFMA tail — 16 edges/wave, A=lrelu(a+b), B=fc2 ----------------
__device__ __forceinline__ void mk_afrag(uint4 ua, const float* bb, bf16x8& ap) {
    float2 t; float z;
    t = bf2(ua.x);
    z = t.x + bb[0]; z = fmaxf(z, 0.01f * z); ap[0] = f2bf_s(z);
    z = t.y + bb[1]; z = fmaxf(z, 0.01f * z); ap[1] = f2bf_s(z);
    t = bf2(ua.y);
    z = t.x + bb[2]; z = fmaxf(z, 0.01f * z); ap[2] = f2bf_s(z);
    z = t.y + bb[3]; z = fmaxf(z, 0.01f * z); ap[3] = f2bf_s(z);
    t = bf2(ua.z);
    z = t.x + bb[4]; z = fmaxf(z, 0.01f * z); ap[4] = f2bf_s(z);
    z = t.y + bb[5]; z = fmaxf(z, 0.01f * z); ap[5] = f2bf_s(z);
    t = bf2(ua.w);
    z = t.x + bb[6]; z = fmaxf(z, 0.01f * z); ap[6] = f2bf_s(z);
    z = t.y + bb[7]; z = fmaxf(z, 0.01f * z); ap[7] = f2bf_s(z);
}

__global__ __launch_bounds__(256) void k_edge(const int* __restrict__ offs,
                                              const int2* __restrict__ csr2,
                                              const unsigned* __restrict__ ab_p,
                                              const unsigned short* __restrict__ fc2m,
                                              const float* __restrict__ fc2_b,
                                              float* __restrict__ out) {
    const int n    = blockIdx.x * 4 + (threadIdx.x >> 6);
    const int lane = threadIdx.x & 63;
    const int c16  = lane & 15;
    const int kg   = lane >> 4;
    bf16x8 bfr0 = *(const bf16x8*)(fc2m + (size_t)lane * 8);
    bf16x8 bfr1 = *(const bf16x8*)(fc2m + (size_t)(64 + lane) * 8);
    const uint4* abv = (const uint4*)ab_p;
    uint4 ub0 = abv[(unsigned)(n * 16 + 8 + kg)];
    uint4 ub1 = abv[(unsigned)(n * 16 + 12 + kg)];
    float bb0[8], bb1[8];
    {
        float2 t;
        t = bf2(ub0.x); bb0[0] = t.x; bb0[1] = t.y;
        t = bf2(ub0.y); bb0[2] = t.x; bb0[3] = t.y;
        t = bf2(ub0.z); bb0[4] = t.x; bb0[5] = t.y;
        t = bf2(ub0.w); bb0[6] = t.x; bb0[7] = t.y;
        t = bf2(ub1.x); bb1[0] = t.x; bb1[1] = t.y;
        t = bf2(ub1.y); bb1[2] = t.x; bb1[3] = t.y;
        t = bf2(ub1.z); bb1[4] = t.x; bb1[5] = t.y;
        t = bf2(ub1.w); bb1[6] = t.x; bb1[7] = t.y;
    }
    const float ob = (c16 < 3) ? fc2_b[c16] : 0.f;
    const int beg = offs[n], end = offs[n + 1];
    for (int base = beg; base < end; base += 16) {
        int slot = base + c16;
        int2 ce = (slot < end) ? csr2[slot] : make_int2(0, 0);
        uint4 ua0 = abv[(unsigned)(ce.x * 16 + kg)];
        uint4 ua1 = abv[(unsigned)(ce.x * 16 + 4 + kg)];
        bf16x8 ap0, ap1;
        mk_afrag(ua0, bb0, ap0);
        mk_afrag(ua1, bb1, ap1);
        f32x4 acc = {};
        acc = __builtin_amdgcn_mfma_f32_16x16x32_bf16(ap0, bfr0, acc, 0, 0, 0);
        acc = __builtin_amdgcn_mfma_f32_16x16x32_bf16(ap1, bfr1, acc, 0, 0, 0);
#pragma unroll
        for (int i = 0; i < 4; ++i) {
            int eid = __shfl(ce.y, kg * 4 + i, 64);
            if (c16 < 3 && (base + kg * 4 + i) < end)
                out[(size_t)eid * 3 + c16] = acc[i] + ob;
        }
    }
}

extern "C" void kernel_launch(void* const* d_in, const int* in_sizes, int n_in,
                              void* d_out, int out_size, void* d_ws, size_t ws_size,
                              hipStream_t stream) {
    const float* x        = (const float*)d_in[0];
    const int*   ei       = (const int*)d_in[1];
    const float* W        = (const float*)d_in[2];
    const float* att_src  = (const float*)d_in[3];
    const float* att_dst  = (const float*)d_in[4];
    const float* conv_b   = (const float*)d_in[5];
    const float* fc1_w    = (const float*)d_in[6];
    const float* fc1_b    = (const float*)d_in[7];
    const float* gamma    = (const float*)d_in[8];
    const float* beta     = (const float*)d_in[9];
    const float* mean     = (const float*)d_in[10];
    const float* var      = (const float*)d_in[11];
    const float* fc2_w    = (const float*)d_in[12];
    const float* fc2_b    = (const float*)d_in[13];
    float*       out      = (float*)d_out;
    char*        ws       = (char*)d_ws;

    const int* src = ei;
    const int* dst = ei + N_EDGES;

    unsigned*       h_p   = (unsigned*)(ws + OFF_HBF);
    unsigned*       h2_p  = (unsigned*)(ws + OFF_H2);
    unsigned*       ab_p  = (unsigned*)(ws + OFF_AB);
    float*          as_   = (float*)(ws + OFF_AS);
    float*          ad_   = (float*)(ws + OFF_AD);
    int*            offs  = (int*)(ws + OFF_OFFS);
    int*            deg   = (int*)(ws + OFF_DEG);
    int*            cur   = (int*)(ws + OFF_CUR);
    int*            part  = (int*)(ws + OFF_PART);
    int2*           csr2  = (int2*)(ws + OFF_CSR2);
    unsigned short* Wt    = (unsigned short*)(ws + OFF_WT);
    unsigned short* fc1t  = (unsigned short*)(ws + OFF_FC1T);
    float*          scale = (float*)(ws + OFF_SCALE);
    float*          cc    = (float*)(ws + OFF_CC);
    unsigned short* fc2m  = (unsigned short*)(ws + OFF_FC2M);

    // prep (tiny; also zeroes deg)
    k_prep<<<235, 256, 0, stream>>>(W, fc1_w, fc1_b, gamma, beta, mean, var, fc2_w,
                                    Wt, fc1t, scale, cc, fc2m, deg);

    // CSR build
    k_hist      <<<1000, 256, 0, stream>>>(dst, deg);
    k_scan_part <<<(N_NODES + 255) / 256, 256, 0, stream>>>(deg, part);
    k_scan_mid  <<<1, 256, 0, stream>>>(part, offs, (N_NODES + 255) / 256);
    k_scan_final<<<(N_NODES + 255) / 256, 256, 0, stream>>>(deg, part, offs, cur);
    k_scatter   <<<1000, 256, 0, stream>>>(src, dst, cur, csr2);

    // node pipeline
    k_mfma_xw<<<N_NODES / 16, 256, 0, stream>>>(x, Wt, att_src, att_dst, h_p, as_, ad_);
    k_agg    <<<N_NODES / 4, 256, 0, stream>>>(h_p, as_, ad_, offs, csr2, conv_b, h2_p);
    k_mfma_uv<<<(N_NODES / 16 + 3) / 4, 256, 0, stream>>>((const unsigned short*)h2_p, fc1t, scale, cc, ab_p);

    // edge tail (MFMA)
    k_edge<<<N_NODES / 4, 256, 0, stream>>>(offs, csr2, ab_p, fc2m, fc2_b, out);
}

// Round 13
// 203.165 us; speedup vs baseline: 1.1271x; 1.0334x over previous
//
#include <hip/hip_runtime.h>
#include <hip/hip_bf16.h>

#define N_NODES 50000
#define N_EDGES 800000
#define F_IN    256
#define C_DIM   64
#define HC      128   // H*C
#define NPG     6250  // nodes per XCD group (N/8)
#define NBLK    196   // scan blocks

typedef __attribute__((ext_vector_type(8))) short bf16x8;
typedef __attribute__((ext_vector_type(4))) float f32x4;

// ---------------- workspace layout (bytes) ----------------
static constexpr size_t OFF_HBF   = 0;           // u32  h packed  [N][64] = 12.8 MB
static constexpr size_t OFF_H2    = 12800000;    // u32  h2 packed [N][64] = 12.8 MB
static constexpr size_t OFF_AB    = 25600000;    // u32  ab packed [N][64] = 12.8 MB
static constexpr size_t OFF_AS    = 38400000;    // f32 [N][2]
static constexpr size_t OFF_AD    = 38800000;
static constexpr size_t OFF_OFFS  = 39200000;    // i32 N+1
static constexpr size_t OFF_DEG   = 39400064;
static constexpr size_t OFF_CUR   = 39600064;
static constexpr size_t OFF_PART  = 39800064;
static constexpr size_t OFF_CSR2  = 39801088;    // int2 [E] (src,eid) = 6.4 MB
static constexpr size_t OFF_WT    = 46201088;    // bf16 Wt   [128][256] = 64 KB
static constexpr size_t OFF_FC1T  = 46266624;    // bf16 fc1t [128][128] = 32 KB
static constexpr size_t OFF_SCALE = 46299392;    // f32 [128]
static constexpr size_t OFF_CC    = 46299904;    // f32 [128]
static constexpr size_t OFF_FC2M  = 46300416;    // bf16 fc2m [2][64][8] = 2 KB

__device__ __forceinline__ float2 bf2(unsigned u) {
    float2 r;
    r.x = __uint_as_float(u << 16);
    r.y = __uint_as_float(u & 0xffff0000u);
    return r;
}
__device__ __forceinline__ unsigned short f2bf(float f) {
    unsigned u = __float_as_uint(f);
    return (unsigned short)((u + 0x7fffu + ((u >> 16) & 1u)) >> 16);  // RNE
}
__device__ __forceinline__ short f2bf_s(float f) {
    __hip_bfloat16 h = __float2bfloat16(f);
    return *reinterpret_cast<short*>(&h);
}
// packed-channel mapping: word q (0..63) of a row holds channels (c0(q), c0(q)+16),
// c0(q) = 32*(q>>4) + (q&15)

// ---------------- prep: Wt, fc1t, fc2m, BN scale/cc, deg zero ----------------
__global__ __launch_bounds__(256) void k_prep(const float* __restrict__ W,
                                              const float* __restrict__ fc1,
                                              const float* __restrict__ fc1_b,
                                              const float* __restrict__ gamma,
                                              const float* __restrict__ beta,
                                              const float* __restrict__ mean,
                                              const float* __restrict__ var,
                                              const float* __restrict__ fc2_w,
                                              unsigned short* __restrict__ Wt,
                                              unsigned short* __restrict__ fc1t,
                                              float* __restrict__ scale,
                                              float* __restrict__ cc,
                                              unsigned short* __restrict__ fc2m,
                                              int* __restrict__ deg) {
    int id = blockIdx.x * 256 + threadIdx.x;
    if (id < N_NODES) deg[id] = 0;
    if (id < 32768) {                       // Wt[n][k] = bf16(W[k][n])
        int n = id >> 8, k = id & 255;
        Wt[id] = f2bf(W[k * HC + n]);
    }
    int id2 = id - 32768;                   // fc1t[j][q], q in h2 storage order
    if (id2 >= 0 && id2 < 16384) {
        int j = id2 >> 7, q = id2 & 127;
        int L = q >> 1, b = q & 1;
        int kch = 32 * (L >> 4) + (L & 15) + 16 * b;
        float v = (j < 64) ? fc1[kch * 64 + j] : fc1[(128 + kch) * 64 + (j - 64)];
        fc1t[id2] = f2bf(v);
    }
    int id3 = id - (32768 + 16384);
    if (id3 >= 0 && id3 < 128) {
        int jj = id3 & 63;
        float s = gamma[jj] * rsqrtf(var[jj] + 1e-5f);
        scale[id3] = s;
        cc[id3] = (id3 < 64) ? 0.f : (fc1_b[jj] - mean[jj]) * s + beta[jj];
    }
    int id4 = id - (32768 + 16384 + 128);   // fc2m[kk][lane][j]: MFMA B-fragment of fc2
    if (id4 >= 0 && id4 < 1024) {
        int kk = id4 >> 9, rem = id4 & 511;
        int lane = rem >> 3, j = rem & 7;
        int q  = kk * 16 + (lane >> 4) * 4 + (j >> 1);
        int ch = 32 * (q >> 4) + (q & 15) + 16 * (j & 1);
        int col = lane & 15;
        float v = (col < 3) ? fc2_w[ch * 3 + col] : 0.f;
        fc2m[id4] = f2bf(v);
    }
}

// ---------------- CSR build (XCD-partitioned, int4 loads) ----------------
__global__ __launch_bounds__(256) void k_hist(const int* __restrict__ dst,
                                              int* __restrict__ deg) {
    const int g  = blockIdx.x & 7;
    const int bi = blockIdx.x >> 3;
    const int lo = g * NPG, hi = lo + NPG;
    const int4* d4 = (const int4*)dst + bi * 1600;
#pragma unroll 1
    for (int it = 0; it < 7; ++it) {
        int idx = it * 256 + threadIdx.x;
        if (idx < 1600) {
            int4 d = d4[idx];
            if (d.x >= lo && d.x < hi) atomicAdd(&deg[d.x], 1);
            if (d.y >= lo && d.y < hi) atomicAdd(&deg[d.y], 1);
            if (d.z >= lo && d.z < hi) atomicAdd(&deg[d.z], 1);
            if (d.w >= lo && d.w < hi) atomicAdd(&deg[d.w], 1);
        }
    }
}

__global__ void k_scan_part(const int* __restrict__ deg, int* __restrict__ part) {
    __shared__ int sd[256];
    int i = blockIdx.x * 256 + threadIdx.x;
    sd[threadIdx.x] = (i < N_NODES) ? deg[i] : 0;
    __syncthreads();
    for (int off = 128; off > 0; off >>= 1) {
        if (threadIdx.x < off) sd[threadIdx.x] += sd[threadIdx.x + off];
        __syncthreads();
    }
    if (threadIdx.x == 0) part[blockIdx.x] = sd[0];
}

// merged: per-block base reduction over parts + local scan (replaces scan_mid+final)
__global__ void k_scan_final(const int* __restrict__ deg, const int* __restrict__ part,
                             int* __restrict__ offs, int* __restrict__ cur) {
    __shared__ int sp[256];
    __shared__ int sd[256];
    const int t = threadIdx.x;
    int pv = (t < NBLK && t < (int)blockIdx.x) ? part[t] : 0;
    sp[t] = pv;
    __syncthreads();
    for (int off = 128; off > 0; off >>= 1) {
        if (t < off) sp[t] += sp[t + off];
        __syncthreads();
    }
    const int base = sp[0];
    __syncthreads();
    int i = blockIdx.x * 256 + t;
    int v = (i < N_NODES) ? deg[i] : 0;
    sd[t] = v;
    __syncthreads();
    for (int off = 1; off < 256; off <<= 1) {
        int u = (t >= off) ? sd[t - off] : 0;
        __syncthreads();
        sd[t] += u;
        __syncthreads();
    }
    if (i < N_NODES) {
        int o = base + sd[t] - v;
        offs[i] = o;
        cur[i]  = o;
        if (i == N_NODES - 1) offs[N_NODES] = o + v;
    }
}

// lean scatter: 8B per edge, XCD-partitioned
__global__ __launch_bounds__(256) void k_scatter(const int* __restrict__ src,
                                                 const int* __restrict__ dst,
                                                 int* __restrict__ cur,
                                                 int2* __restrict__ csr2) {
    const int g  = blockIdx.x & 7;
    const int bi = blockIdx.x >> 3;
    const int lo = g * NPG, hi = lo + NPG;
    const int ebase = bi * 6400;
    const int4* d4 = (const int4*)dst + bi * 1600;
    const int4* s4 = (const int4*)src + bi * 1600;
#pragma unroll 1
    for (int it = 0; it < 7; ++it) {
        int idx = it * 256 + threadIdx.x;
        if (idx < 1600) {
            int4 d = d4[idx];
            int4 s = s4[idx];
            int e = ebase + idx * 4;
            if (d.x >= lo && d.x < hi) { int p = atomicAdd(&cur[d.x], 1); csr2[p] = make_int2(s.x, e);     }
            if (d.y >= lo && d.y < hi) { int p = atomicAdd(&cur[d.y], 1); csr2[p] = make_int2(s.y, e + 1); }
            if (d.z >= lo && d.z < hi) { int p = atomicAdd(&cur[d.z], 1); csr2[p] = make_int2(s.z, e + 2); }
            if (d.w >= lo && d.w < hi) { int p = atomicAdd(&cur[d.w], 1); csr2[p] = make_int2(s.w, e + 3); }
        }
    }
}

// ---------------- MFMA GEMM1: LDS-staged x-tile, cf-split waves, fused att ----------------
__global__ __launch_bounds__(256, 4) void k_mfma_xw(const float* __restrict__ x,
                                                    const unsigned short* __restrict__ Wt,
                                                    const float* __restrict__ att_src,
                                                    const float* __restrict__ att_dst,
                                                    unsigned* __restrict__ h_p,
                                                    float* __restrict__ as_,
                                                    float* __restrict__ ad_) {
    __shared__ float xs[16 * 256];        // slot(rl,j) at (rl*64 + (j^rl)), 16B slots
    __shared__ float sAs[16][2], sAd[16][2];
    const int t    = threadIdx.x;
    const int v    = t >> 6;
    const int lane = t & 63;
    const int c16  = lane & 15;
    const int kg   = lane >> 4;
    const int r0   = blockIdx.x * 16;
    if (t < 32) { ((float*)sAs)[t] = 0.f; ((float*)sAd)[t] = 0.f; }

    {
        const float4* xsrc = (const float4*)(x + (size_t)r0 * F_IN);
        float4* xsl = (float4*)xs;
#pragma unroll
        for (int it = 0; it < 4; ++it) {
            int cidx = it * 256 + t;
            int rl = cidx >> 6, j = cidx & 63;
            float4 val = xsrc[cidx];
            xsl[rl * 64 + (j ^ rl)] = val;
        }
    }
    const int cf0 = 2 * v, cf1 = 2 * v + 1;
    bf16x8 wf0[8], wf1[8];
#pragma unroll
    for (int kk = 0; kk < 8; ++kk) {
        wf0[kk] = *(const bf16x8*)(Wt + (size_t)(cf0 * 16 + c16) * 256 + kk * 32 + kg * 8);
        wf1[kk] = *(const bf16x8*)(Wt + (size_t)(cf1 * 16 + c16) * 256 + kk * 32 + kg * 8);
    }
    __syncthreads();

    f32x4 acc0 = {}, acc1 = {};
#pragma unroll
    for (int kk = 0; kk < 8; ++kk) {
        int j0 = kk * 8 + kg * 2;
        float4 a0 = *(const float4*)(xs + (size_t)(c16 * 64 + (j0 ^ c16)) * 4);
        float4 a1 = *(const float4*)(xs + (size_t)(c16 * 64 + ((j0 + 1) ^ c16)) * 4);
        float fv[8] = {a0.x, a0.y, a0.z, a0.w, a1.x, a1.y, a1.z, a1.w};
        bf16x8 ahi, alo;
#pragma unroll
        for (int q = 0; q < 8; ++q) {
            unsigned u = __float_as_uint(fv[q]);
            float hval = __uint_as_float(u & 0xffff0000u);
            float d = fv[q] - hval;
            ahi[q] = (short)(u >> 16);
            alo[q] = (short)(__float_as_uint(d) >> 16);
        }
        acc0 = __builtin_amdgcn_mfma_f32_16x16x32_bf16(alo, wf0[kk], acc0, 0, 0, 0);
        acc0 = __builtin_amdgcn_mfma_f32_16x16x32_bf16(ahi, wf0[kk], acc0, 0, 0, 0);
        acc1 = __builtin_amdgcn_mfma_f32_16x16x32_bf16(alo, wf1[kk], acc1, 0, 0, 0);
        acc1 = __builtin_amdgcn_mfma_f32_16x16x32_bf16(ahi, wf1[kk], acc1, 0, 0, 0);
    }
#pragma unroll
    for (int i = 0; i < 4; ++i) {
        int row = r0 + kg * 4 + i;
        unsigned pu = (unsigned)f2bf(acc0[i]) | ((unsigned)f2bf(acc1[i]) << 16);
        h_p[(size_t)row * 64 + v * 16 + c16] = pu;
    }
    float ws0 = att_src[cf0 * 16 + c16], ws1 = att_src[cf1 * 16 + c16];
    float wd0 = att_dst[cf0 * 16 + c16], wd1 = att_dst[cf1 * 16 + c16];
    float pas[4], pad[4];
#pragma unroll
    for (int i = 0; i < 4; ++i) {
        pas[i] = acc0[i] * ws0 + acc1[i] * ws1;
        pad[i] = acc0[i] * wd0 + acc1[i] * wd1;
    }
#pragma unroll
    for (int m = 1; m < 16; m <<= 1) {
#pragma unroll
        for (int i = 0; i < 4; ++i) {
            pas[i] += __shfl_xor(pas[i], m, 64);
            pad[i] += __shfl_xor(pad[i], m, 64);
        }
    }
    const int head = v >> 1;
    if (c16 == 0) {
#pragma unroll
        for (int i = 0; i < 4; ++i) {
            atomicAdd(&sAs[kg * 4 + i][head], pas[i]);
            atomicAdd(&sAd[kg * 4 + i][head], pad[i]);
        }
    }
    __syncthreads();
    if (t < 32) {
        int row = t >> 1, hd = t & 1;
        as_[(r0 + row) * 2 + hd] = sAs[row][hd];
        ad_[(r0 + row) * 2 + hd] = sAd[row][hd];
    }
}

// ---------------- k_agg: quarter-wave (16 lanes/edge, uint4), 4 edge-streams/wave ----------------
__global__ __launch_bounds__(256) void k_agg(const unsigned* __restrict__ h_p,
                                             const float* __restrict__ as_,
                                             const float* __restrict__ ad_,
                                             const int* __restrict__ offs,
                                             const int2* __restrict__ csr2,
                                             const float* __restrict__ conv_bias,
                                             unsigned* __restrict__ h2_p) {
    const int n    = blockIdx.x * 4 + (threadIdx.x >> 6);
    const int lane = threadIdx.x & 63;
    const int ql   = lane & 15;       // word-quad index: words 4ql..4ql+3
    const int q    = lane >> 4;       // quarter id = edge slot
    const int hd   = ql >> 3;         // head of this lane's channels
    const float adn = ad_[n * 2 + hd];
    const uint4* h4 = (const uint4*)h_p;
    float a[8] = {};
    float accw = 0.f;
    const int beg = offs[n], end = offs[n + 1];
    int i = beg + q;
    for (; i + 4 < end; i += 8) {     // 2 edges/quarter/iter -> 8 rows in flight per wave
        int s0 = csr2[i].x;
        int s1 = csr2[i + 4].x;
        uint4 u0 = h4[(unsigned)(s0 * 16 + ql)];
        uint4 u1 = h4[(unsigned)(s1 * 16 + ql)];
        float l0 = as_[s0 * 2 + hd] + adn;
        float l1 = as_[s1 * 2 + hd] + adn;
        l0 = fmaxf(l0, 0.2f * l0);
        l1 = fmaxf(l1, 0.2f * l1);
        float w0 = __expf(l0), w1 = __expf(l1);
        float2 t;
        t = bf2(u0.x); a[0] += w0 * t.x; a[1] += w0 * t.y;
        t = bf2(u0.y); a[2] += w0 * t.x; a[3] += w0 * t.y;
        t = bf2(u0.z); a[4] += w0 * t.x; a[5] += w0 * t.y;
        t = bf2(u0.w); a[6] += w0 * t.x; a[7] += w0 * t.y;
        t = bf2(u1.x); a[0] += w1 * t.x; a[1] += w1 * t.y;
        t = bf2(u1.y); a[2] += w1 * t.x; a[3] += w1 * t.y;
        t = bf2(u1.z); a[4] += w1 * t.x; a[5] += w1 * t.y;
        t = bf2(u1.w); a[6] += w1 * t.x; a[7] += w1 * t.y;
        accw += w0 + w1;
    }
    if (i < end) {
        int s0 = csr2[i].x;
        uint4 u0 = h4[(unsigned)(s0 * 16 + ql)];
        float l0 = as_[s0 * 2 + hd] + adn;
        l0 = fmaxf(l0, 0.2f * l0);
        float w0 = __expf(l0);
        float2 t;
        t = bf2(u0.x); a[0] += w0 * t.x; a[1] += w0 * t.y;
        t = bf2(u0.y); a[2] += w0 * t.x; a[3] += w0 * t.y;
        t = bf2(u0.z); a[4] += w0 * t.x; a[5] += w0 * t.y;
        t = bf2(u0.w); a[6] += w0 * t.x; a[7] += w0 * t.y;
        accw += w0;
    }
    // combine quarters
#pragma unroll
    for (int m = 16; m < 64; m <<= 1) {
#pragma unroll
        for (int j = 0; j < 8; ++j) a[j] += __shfl_xor(a[j], m, 64);
        accw += __shfl_xor(accw, m, 64);
    }
    if (q == 0) {
        // self-loop
        float es = as_[n * 2 + hd] + adn;
        es = fmaxf(es, 0.2f * es);
        float wsl = __expf(es);
        uint4 un = h4[(unsigned)(n * 16 + ql)];
        float2 t;
        t = bf2(un.x); a[0] += wsl * t.x; a[1] += wsl * t.y;
        t = bf2(un.y); a[2] += wsl * t.x; a[3] += wsl * t.y;
        t = bf2(un.z); a[4] += wsl * t.x; a[5] += wsl * t.y;
        t = bf2(un.w); a[6] += wsl * t.x; a[7] += wsl * t.y;
        accw += wsl;
        float rinv = 1.f / accw;
        unsigned pw[4];
#pragma unroll
        for (int j = 0; j < 4; ++j) {
            int w = 4 * ql + j;
            int c = 32 * (w >> 4) + (w & 15);
            float o0 = a[2 * j] * rinv + conv_bias[c];
            float o1 = a[2 * j + 1] * rinv + conv_bias[c + 16];
            o0 = fmaxf(o0, 0.01f * o0);
            o1 = fmaxf(o1, 0.01f * o1);
            pw[j] = (unsigned)f2bf(o0) | ((unsigned)f2bf(o1) << 16);
        }
        ((uint4*)h2_p)[(unsigned)(n * 16 + ql)] = make_uint4(pw[0], pw[1], pw[2], pw[3]);
    }
}

// ---------------- MFMA GEMM2: ab = BN-folded h2 @ fc1t^T ----------------
__global__ __launch_bounds__(256) void k_mfma_uv(const unsigned short* __restrict__ h2,
                                                 const unsigned short* __restrict__ fc1t,
                                                 const float* __restrict__ scale,
                                                 const float* __restrict__ cc,
                                                 unsigned* __restrict__ ab_p) {
    const int w = blockIdx.x * 4 + (threadIdx.x >> 6);
    if (w >= N_NODES / 16) return;
    const int lane = threadIdx.x & 63;
    const int c16  = lane & 15;
    const int kg   = lane >> 4;
    const int r0   = w * 16;
    const unsigned short* arow = h2 + (size_t)(r0 + c16) * HC + kg * 8;
    bf16x8 af[4];
#pragma unroll
    for (int kk = 0; kk < 4; ++kk) af[kk] = *(const bf16x8*)(arow + kk * 32);
    f32x4 acc[8] = {};
#pragma unroll
    for (int kk = 0; kk < 4; ++kk) {
        const unsigned short* wp = fc1t + c16 * HC + kk * 32 + kg * 8;
#pragma unroll
        for (int cf = 0; cf < 8; ++cf) {
            bf16x8 b = *(const bf16x8*)(wp + cf * 16 * HC);
            acc[cf] = __builtin_amdgcn_mfma_f32_16x16x32_bf16(af[kk], b, acc[cf], 0, 0, 0);
        }
    }
#pragma unroll
    for (int cf = 0; cf < 8; cf += 2) {
        int j0 = cf * 16 + c16, j1 = j0 + 16;
        float s0 = scale[j0], s1 = scale[j1];
        float q0 = cc[j0],    q1 = cc[j1];
#pragma unroll
        for (int i = 0; i < 4; ++i) {
            int row = r0 + kg * 4 + i;
            unsigned pu = (unsigned)f2bf(acc[cf][i] * s0 + q0)
                        | ((unsigned)f2bf(acc[cf + 1][i] * s1 + q1) << 16);
            ab_p[(size_t)row * 64 + (cf >> 1) * 16 + c16] = pu;
        }
    }
}

// ---------------- k_edge: MFMA tail — 16 edges/wave, A=lrelu(a+b), B=fc2 ----------------
__device__ __forceinline__ void mk_afrag(uint4 ua, const float* bb, bf16x8& ap) {
    float2 t; float z;
    t = bf2(ua.x);
    z = t.x + bb[0]; z = fmaxf(z, 0.01f * z); ap[0] = f2bf_s(z);
    z = t.y + bb[1]; z = fmaxf(z, 0.01f * z); ap[1] = f2bf_s(z);
    t = bf2(ua.y);
    z = t.x + bb[2]; z = fmaxf(z, 0.01f * z); ap[2] = f2bf_s(z);
    z = t.y + bb[3]; z = fmaxf(z, 0.01f * z); ap[3] = f2bf_s(z);
    t = bf2(ua.z);
    z = t.x + bb[4]; z = fmaxf(z, 0.01f * z); ap[4] = f2bf_s(z);
    z = t.y + bb[5]; z = fmaxf(z, 0.01f * z); ap[5] = f2bf_s(z);
    t = bf2(ua.w);
    z = t.x + bb[6]; z = fmaxf(z, 0.01f * z); ap[6] = f2bf_s(z);
    z = t.y + bb[7]; z = fmaxf(z, 0.01f * z); ap[7] = f2bf_s(z);
}

__global__ __launch_bounds__(256) void k_edge(const int* __restrict__ offs,
                                              const int2* __restrict__ csr2,
                                              const unsigned* __restrict__ ab_p,
                                              const unsigned short* __restrict__ fc2m,
                                              const float* __restrict__ fc2_b,
                                              float* __restrict__ out) {
    const int n    = blockIdx.x * 4 + (threadIdx.x >> 6);
    const int lane = threadIdx.x & 63;
    const int c16  = lane & 15;
    const int kg   = lane >> 4;
    bf16x8 bfr0 = *(const bf16x8*)(fc2m + (size_t)lane * 8);
    bf16x8 bfr1 = *(const bf16x8*)(fc2m + (size_t)(64 + lane) * 8);
    const uint4* abv = (const uint4*)ab_p;
    uint4 ub0 = abv[(unsigned)(n * 16 + 8 + kg)];
    uint4 ub1 = abv[(unsigned)(n * 16 + 12 + kg)];
    float bb0[8], bb1[8];
    {
        float2 t;
        t = bf2(ub0.x); bb0[0] = t.x; bb0[1] = t.y;
        t = bf2(ub0.y); bb0[2] = t.x; bb0[3] = t.y;
        t = bf2(ub0.z); bb0[4] = t.x; bb0[5] = t.y;
        t = bf2(ub0.w); bb0[6] = t.x; bb0[7] = t.y;
        t = bf2(ub1.x); bb1[0] = t.x; bb1[1] = t.y;
        t = bf2(ub1.y); bb1[2] = t.x; bb1[3] = t.y;
        t = bf2(ub1.z); bb1[4] = t.x; bb1[5] = t.y;
        t = bf2(ub1.w); bb1[6] = t.x; bb1[7] = t.y;
    }
    const float ob = (c16 < 3) ? fc2_b[c16] : 0.f;
    const int beg = offs[n], end = offs[n + 1];
    for (int base = beg; base < end; base += 16) {
        int slot = base + c16;
        int2 ce = (slot < end) ? csr2[slot] : make_int2(0, 0);
        uint4 ua0 = abv[(unsigned)(ce.x * 16 + kg)];
        uint4 ua1 = abv[(unsigned)(ce.x * 16 + 4 + kg)];
        bf16x8 ap0, ap1;
        mk_afrag(ua0, bb0, ap0);
        mk_afrag(ua1, bb1, ap1);
        f32x4 acc = {};
        acc = __builtin_amdgcn_mfma_f32_16x16x32_bf16(ap0, bfr0, acc, 0, 0, 0);
        acc = __builtin_amdgcn_mfma_f32_16x16x32_bf16(ap1, bfr1, acc, 0, 0, 0);
#pragma unroll
        for (int i = 0; i < 4; ++i) {
            int eid = __shfl(ce.y, kg * 4 + i, 64);
            if (c16 < 3 && (base + kg * 4 + i) < end)
                out[(size_t)eid * 3 + c16] = acc[i] + ob;
        }
    }
}

extern "C" void kernel_launch(void* const* d_in, const int* in_sizes, int n_in,
                              void* d_out, int out_size, void* d_ws, size_t ws_size,
                              hipStream_t stream) {
    const float* x        = (const float*)d_in[0];
    const int*   ei       = (const int*)d_in[1];
    const float* W        = (const float*)d_in[2];
    const float* att_src  = (const float*)d_in[3];
    const float* att_dst  = (const float*)d_in[4];
    const float* conv_b   = (const float*)d_in[5];
    const float* fc1_w    = (const float*)d_in[6];
    const float* fc1_b    = (const float*)d_in[7];
    const float* gamma    = (const float*)d_in[8];
    const float* beta     = (const float*)d_in[9];
    const float* mean     = (const float*)d_in[10];
    const float* var      = (const float*)d_in[11];
    const float* fc2_w    = (const float*)d_in[12];
    const float* fc2_b    = (const float*)d_in[13];
    float*       out      = (float*)d_out;
    char*        ws       = (char*)d_ws;

    const int* src = ei;
    const int* dst = ei + N_EDGES;

    unsigned*       h_p   = (unsigned*)(ws + OFF_HBF);
    unsigned*       h2_p  = (unsigned*)(ws + OFF_H2);
    unsigned*       ab_p  = (unsigned*)(ws + OFF_AB);
    float*          as_   = (float*)(ws + OFF_AS);
    float*          ad_   = (float*)(ws + OFF_AD);
    int*            offs  = (int*)(ws + OFF_OFFS);
    int*            deg   = (int*)(ws + OFF_DEG);
    int*            cur   = (int*)(ws + OFF_CUR);
    int*            part  = (int*)(ws + OFF_PART);
    int2*           csr2  = (int2*)(ws + OFF_CSR2);
    unsigned short* Wt    = (unsigned short*)(ws + OFF_WT);
    unsigned short* fc1t  = (unsigned short*)(ws + OFF_FC1T);
    float*          scale = (float*)(ws + OFF_SCALE);
    float*          cc    = (float*)(ws + OFF_CC);
    unsigned short* fc2m  = (unsigned short*)(ws + OFF_FC2M);

    // prep (tiny; also zeroes deg)
    k_prep<<<235, 256, 0, stream>>>(W, fc1_w, fc1_b, gamma, beta, mean, var, fc2_w,
                                    Wt, fc1t, scale, cc, fc2m, deg);

    // CSR build (scan_mid folded into scan_final)
    k_hist      <<<1000, 256, 0, stream>>>(dst, deg);
    k_scan_part <<<NBLK, 256, 0, stream>>>(deg, part);
    k_scan_final<<<NBLK, 256, 0, stream>>>(deg, part, offs, cur);
    k_scatter   <<<1000, 256, 0, stream>>>(src, dst, cur, csr2);

    // node pipeline
    k_mfma_xw<<<N_NODES / 16, 256, 0, stream>>>(x, Wt, att_src, att_dst, h_p, as_, ad_);
    k_agg    <<<N_NODES / 4, 256, 0, stream>>>(h_p, as_, ad_, offs, csr2, conv_b, h2_p);
    k_mfma_uv<<<(N_NODES / 16 + 3) / 4, 256, 0, stream>>>((const unsigned short*)h2_p, fc1t, scale, cc, ab_p);

    // edge tail (MFMA)
    k_edge<<<N_NODES / 4, 256, 0, stream>>>(offs, csr2, ab_p, fc2m, fc2_b, out);
}